// Round 1
// baseline (441.541 us; speedup 1.0000x reference)
//
#include <hip/hip_runtime.h>

#define TAGS 64
#define MAXT 512
#define NEG  -10000.0f
#define CH   8   // feat prefetch chunk: steps per register buffer

// One wave (64 lanes) per batch. lane = "next" tag.
// Round-7: remove LDS from the recurrence. fv broadcast via 64x v_readlane
// (VALU pipe) instead of write+16x ds_read_b128 broadcast (LDS pipe).
// Rationale: rocprof shows the round-6 pad was DCE'd (LDS_Block_Size=38400),
// so the LDS-contention theory was never tested; all prior ~1330 cyc/step
// variants shared the per-step LDS round-trip. 4 single-wave blocks/CU
// share one in-order LDS pipe: 16 broadcast b128 reads/step/wave ~190
// pipe-cyc + ~120 cyc latency + queueing behind 3 other waves ~ the
// invariant 600-900 cyc that made instruction count irrelevant. Registers
// + readlane have zero latency exposure and zero cross-block contention.
// feats now prefetched straight to registers (coalesced dword loads, 2
// chunks in flight ~ 5600 cyc lead >> 900 cyc HBM latency).
// Max-tree / first-occurrence argmax / terminal / backtrace: unchanged
// from the verified kernel (bit-identical semantics).
__global__ __launch_bounds__(64, 1) void crf_viterbi(
    const float* __restrict__ feats,   // [B, T, K]
    const float* __restrict__ weights, // [K, K] (weights[next][prev])
    const int*   __restrict__ lens,    // [B]
    float*       __restrict__ out,     // [B] scores ++ [B*T] paths (as f32)
    int B, int T)
{
    const int b    = blockIdx.x;
    const int lane = threadIdx.x;              // next tag
    const int len  = lens[b];                  // 1..T

    __shared__ unsigned char  bptr[MAXT * TAGS];   // 32 KB
    __shared__ unsigned short path[MAXT];          // 1 KB
    // LDS ~33.3 KB -> 4 blocks/CU; all 1024 blocks resident from t=0.

    // W row for this lane, as 64 scalars in VGPRs
    float wf[TAGS];
    #pragma unroll
    for (int i = 0; i < 16; ++i) {
        const float4 q = *reinterpret_cast<const float4*>(weights + lane * TAGS + i * 4);
        wf[4*i+0] = q.x; wf[4*i+1] = q.y; wf[4*i+2] = q.z; wf[4*i+3] = q.w;
    }
    const float wEnd = weights[1 * TAGS + lane];  // transition into END

    const float* fb  = feats + (size_t)b * T * TAGS;
    const int    cap = len * TAGS;                // valid dword count

    float nf = (lane == 0) ? 0.0f : NEG;          // fv^(0); START = 0

#define F3(a, b, c) fmaxf(fmaxf((a), (b)), (c))
#define M3(a, b, c) min(min((a), (b)), (c))

    auto step = [&](float feat, int t) {
        // broadcast fv^(t) from lanes to scalars; c = fv + w  (VALU only)
        float c[64];
        #pragma unroll
        for (int p = 0; p < 64; ++p) {
            const float fvp = __uint_as_float(
                __builtin_amdgcn_readlane(__float_as_uint(nf), p));
            c[p] = fvp + wf[p];
        }

        // value-only max: 3-ary tree (v_max3_f32), depth 4 — unchanged
        float v1[22];
        #pragma unroll
        for (int k = 0; k < 21; ++k) v1[k] = F3(c[3*k], c[3*k+1], c[3*k+2]);
        v1[21] = c[63];
        float v2[8];
        #pragma unroll
        for (int k = 0; k < 7; ++k) v2[k] = F3(v1[3*k], v1[3*k+1], v1[3*k+2]);
        v2[7] = v1[21];
        const float v30 = F3(v2[0], v2[1], v2[2]);
        const float v31 = F3(v2[3], v2[4], v2[5]);
        const float v32 = fmaxf(v2[6], v2[7]);
        const float m   = F3(v30, v31, v32);

        nf = m + feat;                 // emission added after max

        // deferred index: first p with c[p]==m (numpy first-occurrence,
        // exact f32 ==; no NaNs in this data) — unchanged
        unsigned e[64];
        #pragma unroll
        for (int p = 0; p < 64; ++p) e[p] = (c[p] == m) ? (unsigned)p : 64u;
        unsigned u1[22];
        #pragma unroll
        for (int k = 0; k < 21; ++k) u1[k] = M3(e[3*k], e[3*k+1], e[3*k+2]);
        u1[21] = e[63];
        unsigned u2[8];
        #pragma unroll
        for (int k = 0; k < 7; ++k) u2[k] = M3(u1[3*k], u1[3*k+1], u1[3*k+2]);
        u2[7] = u1[21];
        const unsigned u30 = M3(u2[0], u2[1], u2[2]);
        const unsigned u31 = M3(u2[3], u2[4], u2[5]);
        const unsigned u32 = min(u2[6], u2[7]);
        const unsigned idx = M3(u30, u31, u32);

        bptr[t * TAGS + lane] = (unsigned char)idx;   // off-critical, 1 byte
    };

    // feat prefetch in registers: chunk c in fcur, chunk c+1 in fnx
    float fcur[CH], fnx[CH];
    #pragma unroll
    for (int i = 0; i < CH; ++i) {
        int o = i * TAGS + lane; if (o >= cap) o = lane;   // clamp: safe addr
        fcur[i] = fb[o];
    }
    #pragma unroll
    for (int i = 0; i < CH; ++i) {
        int o = (CH + i) * TAGS + lane; if (o >= cap) o = lane;
        fnx[i] = fb[o];
    }

    const int nfull = len / CH;
    for (int ch = 0; ch < nfull; ++ch) {
        #pragma unroll
        for (int i = 0; i < CH; ++i) step(fcur[i], ch * CH + i);
        #pragma unroll
        for (int i = 0; i < CH; ++i) fcur[i] = fnx[i];       // static idx only
        #pragma unroll
        for (int i = 0; i < CH; ++i) {
            int o = (ch + 2) * CH * TAGS + i * TAGS + lane; if (o >= cap) o = lane;
            fnx[i] = fb[o];
        }
    }
    const int rem = len - nfull * CH;             // 0..7 remainder steps
    #pragma unroll
    for (int i = 0; i < CH; ++i)                  // static indices (no scratch)
        if (i < rem) step(fcur[i], nfull * CH + i);

    // terminal = fv + W[END][prev]; first-max argmax via shuffle butterfly
    float tv = nf + wEnd;
    int   ti = lane;
    #pragma unroll
    for (int off = 32; off >= 1; off >>= 1) {
        const float ov = __shfl_xor(tv, off);
        const int   oi = __shfl_xor(ti, off);
        if (ov > tv || (ov == tv && oi < ti)) { tv = ov; ti = oi; }
    }
    if (lane == 0) out[b] = tv;
    const int bestlast = ti;                      // uniform across lanes

    // padding region: path[t] = bestlast for t in [len-1, T)
    for (int t = lane; t < T; t += 64)
        if (t >= len - 1) path[t] = (unsigned short)bestlast;
    __builtin_amdgcn_wave_barrier();

    // serial chase (lane 0, LDS-resident backpointers)
    if (lane == 0) {
        int tag = bestlast;
        for (int t = len - 1; t >= 1; --t) {
            tag = bptr[t * TAGS + tag];
            path[t - 1] = (unsigned short)tag;
        }
    }
    __builtin_amdgcn_wave_barrier();

    // coalesced path writeback (tags as float32)
    float* pout = out + B + (size_t)b * T;
    for (int t = lane; t < T; t += 64)
        pout[t] = (float)path[t];
}

extern "C" void kernel_launch(void* const* d_in, const int* in_sizes, int n_in,
                              void* d_out, int out_size, void* d_ws, size_t ws_size,
                              hipStream_t stream) {
    const float* feats   = (const float*)d_in[0];
    const float* weights = (const float*)d_in[1];
    const int*   lens    = (const int*)d_in[2];
    float*       out     = (float*)d_out;

    const int B = in_sizes[2];
    const int T = in_sizes[0] / (B * TAGS);

    crf_viterbi<<<dim3(B), dim3(64), 0, stream>>>(feats, weights, lens, out, B, T);
}